// Round 1
// baseline (1038.528 us; speedup 1.0000x reference)
//
#include <hip/hip_runtime.h>
#include <hip/hip_bf16.h>

typedef __hip_bfloat16 bf16;

static constexpr int D_IN  = 128;   // IN_DIM
static constexpr int D_H   = 256;   // HID
static constexpr int D_CAT = 768;   // 3*HID

__device__ __forceinline__ float lrelu(float v){ return v > 0.f ? v : 0.2f*v; }
__device__ __forceinline__ float b2f(bf16 v){ return __bfloat162float(v); }
__device__ __forceinline__ bf16  f2b(float v){ return __float2bfloat16(v); }
__device__ __forceinline__ void stv(float* p, float v){ *p = v; }
__device__ __forceinline__ void stv(bf16*  p, float v){ *p = f2b(v); }

// ---------------- degree count ----------------
__global__ __launch_bounds__(256) void k_count(const int* __restrict__ col,
                                               int* __restrict__ cnt, int E){
  int e = blockIdx.x*256 + threadIdx.x;
  if (e < E) atomicAdd(&cnt[col[e]], 1);
}

// ---------------- 2-level exclusive scan over cnt -> indptr ----------------
__global__ __launch_bounds__(256) void k_scanA(const int* __restrict__ cnt,
                                               int* __restrict__ indptr,
                                               int* __restrict__ bsum, int N){
  __shared__ int s[256];
  int t = threadIdx.x, i = blockIdx.x*256 + t;
  int v = (i < N) ? cnt[i] : 0;
  s[t] = v; __syncthreads();
  #pragma unroll
  for (int d = 1; d < 256; d <<= 1){
    int tmp = (t >= d) ? s[t-d] : 0;
    __syncthreads();
    s[t] += tmp;
    __syncthreads();
  }
  if (i < N) indptr[i] = s[t] - v;          // block-local exclusive
  if (t == 255) bsum[blockIdx.x] = s[255];  // block total
}

__global__ __launch_bounds__(256) void k_scanB(const int* __restrict__ bsum,
                                               int* __restrict__ boff,
                                               int* __restrict__ indptr,
                                               int nb, int N, int E){
  __shared__ int s[256];
  int t = threadIdx.x;
  int v = (t < nb) ? bsum[t] : 0;
  s[t] = v; __syncthreads();
  #pragma unroll
  for (int d = 1; d < 256; d <<= 1){
    int tmp = (t >= d) ? s[t-d] : 0;
    __syncthreads();
    s[t] += tmp;
    __syncthreads();
  }
  boff[t] = s[t] - v;
  if (t == 0) indptr[N] = E;
}

__global__ __launch_bounds__(256) void k_scanC(int* __restrict__ indptr,
                                               const int* __restrict__ boff, int N){
  int i = blockIdx.x*256 + threadIdx.x;
  if (i < N) indptr[i] += boff[blockIdx.x];
}

// dis = rsqrt(in_degree + 1)   (self-loop included in GCN degree)
__global__ __launch_bounds__(256) void k_dis(const int* __restrict__ cnt,
                                             float* __restrict__ dis, int N){
  int i = blockIdx.x*256 + threadIdx.x;
  if (i < N) dis[i] = rsqrtf((float)cnt[i] + 1.0f);
}

// scatter edge sources into CSR slots (order within a node irrelevant)
__global__ __launch_bounds__(256) void k_fill(const int* __restrict__ row,
                                              const int* __restrict__ col,
                                              const int* __restrict__ indptr,
                                              int* __restrict__ cursor,
                                              int* __restrict__ esrc, int E){
  int e = blockIdx.x*256 + threadIdx.x;
  if (e < E){
    int c = col[e];
    int p = indptr[c] + atomicAdd(&cursor[c], 1);
    esrc[p] = row[e];
  }
}

// ---------------- a_src / a_dst = xa @ att_{src,dst} ----------------
__global__ __launch_bounds__(256) void k_att(const bf16* __restrict__ xa,
                                             const float* __restrict__ att_src,
                                             const float* __restrict__ att_dst,
                                             float* __restrict__ a_src,
                                             float* __restrict__ a_dst, int N){
  int c = blockIdx.x, t = threadIdx.x;
  float v  = b2f(xa[(size_t)c*D_H + t]);
  float s1 = v * att_src[t];
  float s2 = v * att_dst[t];
  #pragma unroll
  for (int off = 32; off > 0; off >>= 1){
    s1 += __shfl_down(s1, off);
    s2 += __shfl_down(s2, off);
  }
  __shared__ float r1[4], r2[4];
  int w = t >> 6, l = t & 63;
  if (l == 0){ r1[w] = s1; r2[w] = s2; }
  __syncthreads();
  if (t == 0){
    a_src[c] = r1[0]+r1[1]+r1[2]+r1[3];
    a_dst[c] = r2[0]+r2[1]+r2[2]+r2[3];
  }
}

// ---------------- fused per-node aggregation (GCN + GAT + SAGE-mean) --------
// one block = one target node; thread t owns hidden dim t
__global__ __launch_bounds__(256) void k_aggregate(
    const int* __restrict__ indptr, const int* __restrict__ esrc,
    const bf16* __restrict__ xg, const bf16* __restrict__ xa,
    const float* __restrict__ x,
    const float* __restrict__ a_src, const float* __restrict__ a_dst,
    const float* __restrict__ dis,
    const float* __restrict__ b_gcn, const float* __restrict__ b_gat,
    bf16* __restrict__ H, bf16* __restrict__ meanb, int N)
{
  int c = blockIdx.x;
  if (c >= N) return;
  int t = threadIdx.x;
  int beg = indptr[c], end = indptr[c+1];
  float adst = a_dst[c];
  float dc   = dis[c];
  float eself = lrelu(a_src[c] + adst);

  // pass 1: GAT row max (scalar, redundant across threads; loads broadcast)
  float m = eself;
  for (int e = beg; e < end; ++e){
    int s = esrc[e];
    m = fmaxf(m, lrelu(a_src[s] + adst));
  }

  // pass 2: fused accumulation (self-loop terms seeded)
  float p0 = __expf(eself - m);
  float z  = p0;
  float gs = dc * b2f(xg[(size_t)c*D_H + t]);  // GCN: dis[c] factored out at end
  float ga = p0 * b2f(xa[(size_t)c*D_H + t]);
  float sg = 0.f;
  for (int e = beg; e < end; ++e){
    int s = esrc[e];
    float dsrc = dis[s];
    float pe   = __expf(lrelu(a_src[s] + adst) - m);
    z += pe;
    gs = fmaf(dsrc, b2f(xg[(size_t)s*D_H + t]), gs);
    ga = fmaf(pe,   b2f(xa[(size_t)s*D_H + t]), ga);
    if (t < D_IN) sg += x[(size_t)s*D_IN + t];
  }

  size_t ho = (size_t)c*D_CAT;
  H[ho + t]        = f2b(fmaxf(dc*gs + b_gcn[t], 0.f));                 // relu(h_gcn)
  H[ho + D_H + t]  = f2b(fmaxf(ga/(z + 1e-16f) + b_gat[t], 0.f));       // relu(h_gat)
  if (t < D_IN){
    float cf = (float)(end - beg);
    meanb[(size_t)c*D_IN + t] = f2b(sg / fmaxf(cf, 1.f));               // SAGE mean
  }
}

// ---------------- tiled fp32 GEMM: C = A*B (+addsrc)(+bias)(relu) ----------
// A: [M,K] (float or bf16), B: [K,N] fp32, C: [M,N] (float or bf16)
template<typename T> struct Load8;
template<> struct Load8<float>{
  static __device__ __forceinline__ void go(const float* p, float* o){
    const float4* p4 = reinterpret_cast<const float4*>(p);
    float4 a = p4[0], b = p4[1];
    o[0]=a.x; o[1]=a.y; o[2]=a.z; o[3]=a.w;
    o[4]=b.x; o[5]=b.y; o[6]=b.z; o[7]=b.w;
  }
};
template<> struct Load8<bf16>{
  static __device__ __forceinline__ void go(const bf16* p, float* o){
    const uint4* p4 = reinterpret_cast<const uint4*>(p);
    uint4 u = *p4;
    unsigned int w[4] = {u.x, u.y, u.z, u.w};
    #pragma unroll
    for (int i = 0; i < 4; ++i){
      o[2*i]   = __uint_as_float(w[i] << 16);
      o[2*i+1] = __uint_as_float(w[i] & 0xffff0000u);
    }
  }
};

template<typename TA, typename TC, bool RELU, bool HASADD, bool HASBIAS>
__global__ __launch_bounds__(256) void k_gemm(
    const TA* __restrict__ A, int lda,
    const float* __restrict__ B, int ldb,
    const bf16* __restrict__ addsrc, int ldadd,
    const float* __restrict__ bias,
    TC* __restrict__ C, int ldc,
    int Mdim, int Ndim, int Kdim)
{
  constexpr int BM = 128, BN = 128, BK = 16;
  __shared__ float As[BK][BM];   // [k][m]
  __shared__ float Bs[BK][BN];   // [k][n]
  int tid = threadIdx.x;
  int bm = blockIdx.y*BM, bn = blockIdx.x*BN;
  int tx = tid & 15, ty = tid >> 4;

  float acc[8][8] = {};

  int ar  = tid >> 1;          // A stage: row 0..127
  int ak  = (tid & 1) * 8;     //          k 0 or 8
  int bk  = tid >> 4;          // B stage: k 0..15
  int bn8 = (tid & 15) * 8;    //          col group

  for (int k0 = 0; k0 < Kdim; k0 += BK){
    float av[8];
    int row = bm + ar;
    if (row < Mdim){
      Load8<TA>::go(A + (size_t)row*lda + k0 + ak, av);
    } else {
      #pragma unroll
      for (int j = 0; j < 8; ++j) av[j] = 0.f;
    }
    #pragma unroll
    for (int j = 0; j < 8; ++j) As[ak + j][ar] = av[j];

    float bv[8];
    Load8<float>::go(B + (size_t)(k0 + bk)*ldb + bn + bn8, bv);
    #pragma unroll
    for (int j = 0; j < 8; ++j) Bs[bk][bn8 + j] = bv[j];

    __syncthreads();
    #pragma unroll
    for (int kk = 0; kk < BK; ++kk){
      const float4* a4 = reinterpret_cast<const float4*>(&As[kk][ty*8]);
      const float4* b4 = reinterpret_cast<const float4*>(&Bs[kk][tx*8]);
      float4 a0 = a4[0], a1 = a4[1], b0 = b4[0], b1 = b4[1];
      float a[8] = {a0.x,a0.y,a0.z,a0.w,a1.x,a1.y,a1.z,a1.w};
      float b[8] = {b0.x,b0.y,b0.z,b0.w,b1.x,b1.y,b1.z,b1.w};
      #pragma unroll
      for (int i = 0; i < 8; ++i)
        #pragma unroll
        for (int j = 0; j < 8; ++j)
          acc[i][j] = fmaf(a[i], b[j], acc[i][j]);
    }
    __syncthreads();
  }

  #pragma unroll
  for (int i = 0; i < 8; ++i){
    int row = bm + ty*8 + i;
    if (row >= Mdim) continue;
    #pragma unroll
    for (int j = 0; j < 8; ++j){
      int colc = bn + tx*8 + j;
      float v = acc[i][j];
      if (HASADD)  v += b2f(addsrc[(size_t)row*ldadd + colc]);
      if (HASBIAS) v += bias[colc];
      if (RELU)    v = fmaxf(v, 0.f);
      stv(&C[(size_t)row*ldc + colc], v);
    }
  }
}

// ---------------- host launch ----------------
static inline char* carve(char*& p, size_t bytes){
  char* r = p;
  p += (bytes + 255) & ~(size_t)255;
  return r;
}

extern "C" void kernel_launch(void* const* d_in, const int* in_sizes, int n_in,
                              void* d_out, int out_size, void* d_ws, size_t ws_size,
                              hipStream_t stream) {
  const float* x       = (const float*)d_in[0];
  const int*   ei      = (const int*)  d_in[1];
  const float* W_gcn   = (const float*)d_in[2];
  const float* b_gcn   = (const float*)d_in[3];
  const float* W_gat   = (const float*)d_in[4];
  const float* att_src = (const float*)d_in[5];
  const float* att_dst = (const float*)d_in[6];
  const float* b_gat   = (const float*)d_in[7];
  const float* W_sage_l= (const float*)d_in[8];
  const float* b_sage_l= (const float*)d_in[9];
  const float* W_sage_r= (const float*)d_in[10];
  const float* W_fus   = (const float*)d_in[11];
  const float* b_fus   = (const float*)d_in[12];

  const int N = in_sizes[0] / D_IN;   // 50000
  const int E = in_sizes[1] / 2;      // 800000
  const int* erow = ei;
  const int* ecol = ei + E;

  // workspace carve (~171 MB total)
  char* p = (char*)d_ws;
  bf16*  xg     = (bf16*) carve(p, (size_t)N*D_H*2);
  bf16*  xa     = (bf16*) carve(p, (size_t)N*D_H*2);
  bf16*  xr     = (bf16*) carve(p, (size_t)N*D_H*2);
  bf16*  H      = (bf16*) carve(p, (size_t)N*D_CAT*2);
  bf16*  meanb  = (bf16*) carve(p, (size_t)N*D_IN*2);
  float* a_src  = (float*)carve(p, (size_t)N*4);
  float* a_dst  = (float*)carve(p, (size_t)N*4);
  float* dis    = (float*)carve(p, (size_t)N*4);
  int*   cnt    = (int*)  carve(p, (size_t)N*4);
  int*   cursor = (int*)  carve(p, (size_t)N*4);
  int*   indptr = (int*)  carve(p, (size_t)(N+1)*4);
  int*   bsum   = (int*)  carve(p, 256*4);
  int*   boff   = (int*)  carve(p, 256*4);
  int*   esrc   = (int*)  carve(p, (size_t)E*4);
  (void)ws_size; (void)n_in; (void)out_size;

  hipMemsetAsync(cnt,    0, (size_t)N*4, stream);
  hipMemsetAsync(cursor, 0, (size_t)N*4, stream);

  const int nb = (N + 255) / 256;
  const int eb = (E + 255) / 256;

  // CSR build
  k_count<<<eb, 256, 0, stream>>>(ecol, cnt, E);
  k_scanA<<<nb, 256, 0, stream>>>(cnt, indptr, bsum, N);
  k_scanB<<<1, 256, 0, stream>>>(bsum, boff, indptr, nb, N, E);
  k_scanC<<<nb, 256, 0, stream>>>(indptr, boff, N);
  k_dis  <<<nb, 256, 0, stream>>>(cnt, dis, N);
  k_fill <<<eb, 256, 0, stream>>>(erow, ecol, indptr, cursor, esrc, E);

  // feature transforms: xg = x@W_gcn, xa = x@W_gat, xr = x@W_sage_r  (bf16 out)
  dim3 g1(D_H/128, (N + 127)/128);
  k_gemm<float, bf16, false, false, false><<<g1, 256, 0, stream>>>(
      x, D_IN, W_gcn, D_H, nullptr, 0, nullptr, xg, D_H, N, D_H, D_IN);
  k_gemm<float, bf16, false, false, false><<<g1, 256, 0, stream>>>(
      x, D_IN, W_gat, D_H, nullptr, 0, nullptr, xa, D_H, N, D_H, D_IN);
  k_gemm<float, bf16, false, false, false><<<g1, 256, 0, stream>>>(
      x, D_IN, W_sage_r, D_H, nullptr, 0, nullptr, xr, D_H, N, D_H, D_IN);

  // attention logits
  k_att<<<N, 256, 0, stream>>>(xa, att_src, att_dst, a_src, a_dst, N);

  // fused edge aggregation -> H[:,0:512] (gcn|gat) + SAGE mean
  k_aggregate<<<N, 256, 0, stream>>>(indptr, esrc, xg, xa, x,
                                     a_src, a_dst, dis, b_gcn, b_gat,
                                     H, meanb, N);

  // SAGE: H[:,512:768] = relu(mean@W_sage_l + xr + b_sage_l)
  k_gemm<bf16, bf16, true, true, true><<<g1, 256, 0, stream>>>(
      meanb, D_IN, W_sage_l, D_H, xr, D_H, b_sage_l, H + 512, D_CAT, N, D_H, D_IN);

  // final: out = H @ W_fus + b_fus   (fp32 out)
  k_gemm<bf16, float, false, false, true><<<g1, 256, 0, stream>>>(
      H, D_CAT, W_fus, D_H, nullptr, 0, b_fus, (float*)d_out, D_H, N, D_H, D_CAT);
}

// Round 4
// 522.306 us; speedup vs baseline: 1.9884x; 1.9884x over previous
//
#include <hip/hip_runtime.h>
#include <hip/hip_bf16.h>

typedef __hip_bfloat16 bf16;
typedef short bf16x8 __attribute__((ext_vector_type(8)));   // 8 bf16 (4 VGPRs)
typedef float f32x4  __attribute__((ext_vector_type(4)));

static constexpr int D_IN  = 128;
static constexpr int D_H   = 256;
static constexpr int D_CAT = 768;

__device__ __forceinline__ float lrelu(float v){ return v > 0.f ? v : 0.2f*v; }
__device__ __forceinline__ float b2f(bf16 v){ return __bfloat162float(v); }
__device__ __forceinline__ bf16  f2b(float v){ return __float2bfloat16(v); }

__device__ __forceinline__ void gload_lds16(const void* g, void* l){
  __builtin_amdgcn_global_load_lds(
      (const __attribute__((address_space(1))) unsigned*)g,
      (__attribute__((address_space(3))) unsigned*)l, 16, 0, 0);
}

// ================= CSR build =================
__global__ __launch_bounds__(256) void k_count(const int* __restrict__ col,
                                               int* __restrict__ cnt, int E){
  int e = blockIdx.x*256 + threadIdx.x;
  if (e < E) atomicAdd(&cnt[col[e]], 1);
}

__global__ __launch_bounds__(256) void k_scanA(const int* __restrict__ cnt,
                                               int* __restrict__ indptr,
                                               int* __restrict__ bsum, int N){
  __shared__ int s[256];
  int t = threadIdx.x, i = blockIdx.x*256 + t;
  int v = (i < N) ? cnt[i] : 0;
  s[t] = v; __syncthreads();
  #pragma unroll
  for (int d = 1; d < 256; d <<= 1){
    int tmp = (t >= d) ? s[t-d] : 0;
    __syncthreads();
    s[t] += tmp;
    __syncthreads();
  }
  if (i < N) indptr[i] = s[t] - v;
  if (t == 255) bsum[blockIdx.x] = s[255];
}

__global__ __launch_bounds__(256) void k_scanB(const int* __restrict__ bsum,
                                               int* __restrict__ boff,
                                               int* __restrict__ indptr,
                                               int nb, int N, int E){
  __shared__ int s[256];
  int t = threadIdx.x;
  int v = (t < nb) ? bsum[t] : 0;
  s[t] = v; __syncthreads();
  #pragma unroll
  for (int d = 1; d < 256; d <<= 1){
    int tmp = (t >= d) ? s[t-d] : 0;
    __syncthreads();
    s[t] += tmp;
    __syncthreads();
  }
  boff[t] = s[t] - v;
  if (t == 0) indptr[N] = E;
}

__global__ __launch_bounds__(256) void k_scanC(int* __restrict__ indptr,
                                               const int* __restrict__ boff, int N){
  int i = blockIdx.x*256 + threadIdx.x;
  if (i < N) indptr[i] += boff[blockIdx.x];
}

__global__ __launch_bounds__(256) void k_dis(const int* __restrict__ cnt,
                                             float* __restrict__ dis, int N){
  int i = blockIdx.x*256 + threadIdx.x;
  if (i < N) dis[i] = rsqrtf((float)cnt[i] + 1.0f);
}

__global__ __launch_bounds__(256) void k_fill(const int* __restrict__ row,
                                              const int* __restrict__ col,
                                              const int* __restrict__ indptr,
                                              int* __restrict__ cursor,
                                              int* __restrict__ esrc, int E){
  int e = blockIdx.x*256 + threadIdx.x;
  if (e < E){
    int c = col[e];
    int p = indptr[c] + atomicAdd(&cursor[c], 1);
    esrc[p] = row[e];
  }
}

// ================= prep: casts / weight transposes =================
__global__ __launch_bounds__(256) void k_cast(const float* __restrict__ x,
                                              bf16* __restrict__ xb, int n4){
  int i = blockIdx.x*256 + threadIdx.x;
  if (i < n4){
    float4 v = reinterpret_cast<const float4*>(x)[i];
    bf16* o = xb + (size_t)i*4;
    o[0]=f2b(v.x); o[1]=f2b(v.y); o[2]=f2b(v.z); o[3]=f2b(v.w);
  }
}

// Bt[n][k] = W_*[k][n&255] for n-range [0,768)  (W: [128][256] fp32 row-major)
__global__ __launch_bounds__(128) void k_pack3(const float* __restrict__ Wg,
                                               const float* __restrict__ Wa,
                                               const float* __restrict__ Wr,
                                               bf16* __restrict__ Bt){
  int n = blockIdx.x, k = threadIdx.x;
  const float* W = (n < 256) ? Wg : ((n < 512) ? Wa : Wr);
  Bt[(size_t)n*D_IN + k] = f2b(W[(size_t)k*D_H + (n & 255)]);
}

// Bt[n][k] = W[k][n]   (W: [K][256] fp32) -> Bt [256][K] bf16
__global__ __launch_bounds__(256) void k_packT(const float* __restrict__ W,
                                               bf16* __restrict__ Bt, int K){
  int n = blockIdx.x;
  for (int k = threadIdx.x; k < K; k += 256)
    Bt[(size_t)n*K + k] = f2b(W[(size_t)k*D_H + n]);
}

// ================= a_src / a_dst =================
__global__ __launch_bounds__(256) void k_att(const bf16* __restrict__ XT,
                                             const float* __restrict__ att_src,
                                             const float* __restrict__ att_dst,
                                             float* __restrict__ a_src,
                                             float* __restrict__ a_dst, int N){
  int c = blockIdx.x, t = threadIdx.x;
  float v  = b2f(XT[(size_t)c*D_CAT + D_H + t]);   // xa = XT[:,256:512]
  float s1 = v * att_src[t];
  float s2 = v * att_dst[t];
  #pragma unroll
  for (int off = 32; off > 0; off >>= 1){
    s1 += __shfl_down(s1, off);
    s2 += __shfl_down(s2, off);
  }
  __shared__ float r1[4], r2[4];
  int w = t >> 6, l = t & 63;
  if (l == 0){ r1[w] = s1; r2[w] = s2; }
  __syncthreads();
  if (t == 0){
    a_src[c] = r1[0]+r1[1]+r1[2]+r1[3];
    a_dst[c] = r2[0]+r2[1]+r2[2]+r2[3];
  }
}

// ================= fused aggregation =================
// block = target node; thread t = hidden dim t. Edge coefficients staged
// through LDS in chunks of 256 (computed once, broadcast to all dims).
__global__ __launch_bounds__(256) void k_aggregate(
    const int* __restrict__ indptr, const int* __restrict__ esrc,
    const bf16* __restrict__ XT,     // [N,768]: xg|xa|xr
    const bf16* __restrict__ xb,     // [N,128]
    const float* __restrict__ a_src, const float* __restrict__ a_dst,
    const float* __restrict__ dis,
    const float* __restrict__ b_gcn, const float* __restrict__ b_gat,
    bf16* __restrict__ H, bf16* __restrict__ meanb, int N)
{
  int c = blockIdx.x;
  if (c >= N) return;
  int t = threadIdx.x;
  int beg = indptr[c], end = indptr[c+1];
  float adst = a_dst[c], dc = dis[c];
  float eself = lrelu(a_src[c] + adst);

  __shared__ int   s_src[256];
  __shared__ float s_pe[256];
  __shared__ float s_ds[256];
  __shared__ float red[8];

  // ---- parallel max over incoming edges ----
  float lm = eself;
  for (int e = beg + t; e < end; e += 256)
    lm = fmaxf(lm, lrelu(a_src[esrc[e]] + adst));
  #pragma unroll
  for (int o = 32; o > 0; o >>= 1) lm = fmaxf(lm, __shfl_down(lm, o));
  if ((t & 63) == 0) red[t >> 6] = lm;
  __syncthreads();
  float m = fmaxf(fmaxf(red[0], red[1]), fmaxf(red[2], red[3]));

  // ---- chunked fused accumulation ----
  float p0 = __expf(eself - m);
  float z_loc = (t == 0) ? p0 : 0.f;
  const bf16* xg = XT;
  const bf16* xa = XT + D_H;
  float gs = dc * b2f(xg[(size_t)c*D_CAT + t]);
  float ga = p0 * b2f(xa[(size_t)c*D_CAT + t]);
  float sg = 0.f;

  for (int ch0 = beg; ch0 < end; ch0 += 256){
    int n = min(256, end - ch0);
    __syncthreads();                     // LDS reuse guard
    if (t < n){
      int s = esrc[ch0 + t];
      float pe = __expf(lrelu(a_src[s] + adst) - m);
      s_src[t] = s; s_pe[t] = pe; s_ds[t] = dis[s];
      z_loc += pe;
    }
    __syncthreads();
    int i = 0;
    for (; i + 1 < n; i += 2){
      int   s0 = s_src[i],   s1 = s_src[i+1];
      float pe0 = s_pe[i],   pe1 = s_pe[i+1];
      float d0 = s_ds[i],    d1 = s_ds[i+1];
      float g0 = b2f(xg[(size_t)s0*D_CAT + t]);
      float g1 = b2f(xg[(size_t)s1*D_CAT + t]);
      float a0 = b2f(xa[(size_t)s0*D_CAT + t]);
      float a1 = b2f(xa[(size_t)s1*D_CAT + t]);
      gs = fmaf(d0, g0, gs);  gs = fmaf(d1, g1, gs);
      ga = fmaf(pe0, a0, ga); ga = fmaf(pe1, a1, ga);
      if (t < D_IN)
        sg += b2f(xb[(size_t)s0*D_IN + t]) + b2f(xb[(size_t)s1*D_IN + t]);
    }
    for (; i < n; ++i){
      int   s0 = s_src[i];
      float pe0 = s_pe[i], d0 = s_ds[i];
      gs = fmaf(d0,  b2f(xg[(size_t)s0*D_CAT + t]), gs);
      ga = fmaf(pe0, b2f(xa[(size_t)s0*D_CAT + t]), ga);
      if (t < D_IN) sg += b2f(xb[(size_t)s0*D_IN + t]);
    }
  }

  // ---- z reduction ----
  #pragma unroll
  for (int o = 32; o > 0; o >>= 1) z_loc += __shfl_down(z_loc, o);
  __syncthreads();
  if ((t & 63) == 0) red[t >> 6] = z_loc;
  __syncthreads();
  float z = red[0] + red[1] + red[2] + red[3];

  size_t ho = (size_t)c * D_CAT;
  H[ho + t]       = f2b(fmaxf(dc*gs + b_gcn[t], 0.f));
  H[ho + D_H + t] = f2b(fmaxf(ga/(z + 1e-16f) + b_gat[t], 0.f));
  if (t < D_IN){
    float cf = (float)(end - beg);
    meanb[(size_t)c*D_IN + t] = f2b(sg / fmaxf(cf, 1.f));
  }
}

// ================= MFMA GEMM =================
// C[M,Ncols] = A[M,K]bf16 @ B (given as Bt[Ncols,K] bf16), 128x128 tile, BK=64.
// LDS tiles stored with XOR-swizzle: slot (r, g') holds global col-group g'^(r&7).
// EPI: 0 plain->bf16, 1 (+addsrc+bias, relu)->bf16, 2 (+bias)->fp32
template<int EPI>
__global__ __launch_bounds__(256) void k_mfma(
    const bf16* __restrict__ A, int lda,
    const bf16* __restrict__ Bt,
    const bf16* __restrict__ addsrc, int ldadd,
    const float* __restrict__ bias,
    void* __restrict__ Cv, int ldc,
    int M, int K)
{
  __shared__ short As[128*64];
  __shared__ short Bs[128*64];
  int tid  = threadIdx.x;
  int bm   = blockIdx.y*128, bn = blockIdx.x*128;
  int wave = tid >> 6, lane = tid & 63;
  int wr   = (wave >> 1)*64, wc = (wave & 1)*64;
  int l15  = lane & 15, l4 = lane >> 4;

  f32x4 acc[4][4] = {};

  for (int k0 = 0; k0 < K; k0 += 64){
    #pragma unroll
    for (int i = 0; i < 4; ++i){
      int slot = i*256 + tid;
      int r = slot >> 3, gp = slot & 7;
      int gk = gp ^ (r & 7);                    // inverse-swizzled source group
      int ra = bm + r; ra = (ra < M) ? ra : (M-1);
      gload_lds16(A  + (size_t)ra*lda + k0 + gk*8, As + (size_t)slot*8);
      gload_lds16(Bt + (size_t)(bn + r)*K + k0 + gk*8, Bs + (size_t)slot*8);
    }
    __syncthreads();

    #pragma unroll
    for (int kk = 0; kk < 2; ++kk){
      bf16x8 af[4], bfr[4];
      #pragma unroll
      for (int mi = 0; mi < 4; ++mi){
        int r = wr + mi*16 + l15;
        int gk = kk*4 + l4;
        af[mi] = *(const bf16x8*)(As + r*64 + ((gk ^ (r & 7))*8));
      }
      #pragma unroll
      for (int ni = 0; ni < 4; ++ni){
        int r = wc + ni*16 + l15;
        int gk = kk*4 + l4;
        bfr[ni] = *(const bf16x8*)(Bs + r*64 + ((gk ^ (r & 7))*8));
      }
      #pragma unroll
      for (int mi = 0; mi < 4; ++mi)
        #pragma unroll
        for (int ni = 0; ni < 4; ++ni)
          acc[mi][ni] = __builtin_amdgcn_mfma_f32_16x16x32_bf16(
                            af[mi], bfr[ni], acc[mi][ni], 0, 0, 0);
    }
    __syncthreads();
  }

  #pragma unroll
  for (int mi = 0; mi < 4; ++mi){
    #pragma unroll
    for (int r = 0; r < 4; ++r){
      int row = bm + wr + mi*16 + l4*4 + r;
      if (row >= M) continue;
      #pragma unroll
      for (int ni = 0; ni < 4; ++ni){
        int col = bn + wc + ni*16 + l15;
        float v = acc[mi][ni][r];
        if (EPI == 1)
          v = fmaxf(v + b2f(addsrc[(size_t)row*ldadd + col]) + bias[col], 0.f);
        if (EPI == 2) v += bias[col];
        if (EPI == 2) ((float*)Cv)[(size_t)row*ldc + col] = v;
        else          ((bf16*) Cv)[(size_t)row*ldc + col] = f2b(v);
      }
    }
  }
}

// ================= host =================
static inline char* carve(char*& p, size_t bytes){
  char* r = p;
  p += (bytes + 255) & ~(size_t)255;
  return r;
}

extern "C" void kernel_launch(void* const* d_in, const int* in_sizes, int n_in,
                              void* d_out, int out_size, void* d_ws, size_t ws_size,
                              hipStream_t stream) {
  const float* x        = (const float*)d_in[0];
  const int*   ei       = (const int*)  d_in[1];
  const float* W_gcn    = (const float*)d_in[2];
  const float* b_gcn    = (const float*)d_in[3];
  const float* W_gat    = (const float*)d_in[4];
  const float* att_src  = (const float*)d_in[5];
  const float* att_dst  = (const float*)d_in[6];
  const float* b_gat    = (const float*)d_in[7];
  const float* W_sage_l = (const float*)d_in[8];
  const float* b_sage_l = (const float*)d_in[9];
  const float* W_sage_r = (const float*)d_in[10];
  const float* W_fus    = (const float*)d_in[11];
  const float* b_fus    = (const float*)d_in[12];

  const int N = in_sizes[0] / D_IN;
  const int E = in_sizes[1] / 2;
  const int* erow = ei;
  const int* ecol = ei + E;

  char* p = (char*)d_ws;
  bf16*  XT     = (bf16*) carve(p, (size_t)N*D_CAT*2);   // xg|xa|xr
  bf16*  H      = (bf16*) carve(p, (size_t)N*D_CAT*2);
  bf16*  xb     = (bf16*) carve(p, (size_t)N*D_IN*2);
  bf16*  meanb  = (bf16*) carve(p, (size_t)N*D_IN*2);
  bf16*  BtA    = (bf16*) carve(p, (size_t)D_CAT*D_IN*2);   // [768][128]
  bf16*  BtSL   = (bf16*) carve(p, (size_t)D_H*D_IN*2);     // [256][128]
  bf16*  BtF    = (bf16*) carve(p, (size_t)D_H*D_CAT*2);    // [256][768]
  float* a_src  = (float*)carve(p, (size_t)N*4);
  float* a_dst  = (float*)carve(p, (size_t)N*4);
  float* dis    = (float*)carve(p, (size_t)N*4);
  int*   cnt    = (int*)  carve(p, (size_t)N*4);
  int*   cursor = (int*)  carve(p, (size_t)N*4);
  int*   indptr = (int*)  carve(p, (size_t)(N+1)*4);
  int*   bsum   = (int*)  carve(p, 256*4);
  int*   boff   = (int*)  carve(p, 256*4);
  int*   esrc   = (int*)  carve(p, (size_t)E*4);
  (void)ws_size; (void)n_in; (void)out_size;

  hipMemsetAsync(cnt,    0, (size_t)N*4, stream);
  hipMemsetAsync(cursor, 0, (size_t)N*4, stream);

  const int nb = (N + 255) / 256;
  const int eb = (E + 255) / 256;

  // prep
  k_cast <<<(N*D_IN/4 + 255)/256, 256, 0, stream>>>(x, xb, N*D_IN/4);
  k_pack3<<<D_CAT, 128, 0, stream>>>(W_gcn, W_gat, W_sage_r, BtA);
  k_packT<<<D_H, 256, 0, stream>>>(W_sage_l, BtSL, D_IN);
  k_packT<<<D_H, 256, 0, stream>>>(W_fus,    BtF,  D_CAT);

  // CSR
  k_count<<<eb, 256, 0, stream>>>(ecol, cnt, E);
  k_scanA<<<nb, 256, 0, stream>>>(cnt, indptr, bsum, N);
  k_scanB<<<1, 256, 0, stream>>>(bsum, boff, indptr, nb, N, E);
  k_scanC<<<nb, 256, 0, stream>>>(indptr, boff, N);
  k_dis  <<<nb, 256, 0, stream>>>(cnt, dis, N);
  k_fill <<<eb, 256, 0, stream>>>(erow, ecol, indptr, cursor, esrc, E);

  const int mtiles = (N + 127) / 128;

  // T1: XT = xb @ [W_gcn|W_gat|W_sage_r]
  k_mfma<0><<<dim3(D_CAT/128, mtiles), 256, 0, stream>>>(
      xb, D_IN, BtA, nullptr, 0, nullptr, XT, D_CAT, N, D_IN);

  k_att<<<N, 256, 0, stream>>>(XT, att_src, att_dst, a_src, a_dst, N);

  k_aggregate<<<N, 256, 0, stream>>>(indptr, esrc, XT, xb,
                                     a_src, a_dst, dis, b_gcn, b_gat,
                                     H, meanb, N);

  // T2: H[:,512:768] = relu(meanb @ W_sage_l + xr + b_sage_l)
  k_mfma<1><<<dim3(D_H/128, mtiles), 256, 0, stream>>>(
      meanb, D_IN, BtSL, XT + 2*D_H, D_CAT, b_sage_l, H + 2*D_H, D_CAT, N, D_IN);

  // T3: out = H @ W_fus + b_fus (fp32)
  k_mfma<2><<<dim3(D_H/128, mtiles), 256, 0, stream>>>(
      H, D_CAT, BtF, nullptr, 0, b_fus, (float*)d_out, D_H, N, D_CAT);
}

// Round 5
// 423.485 us; speedup vs baseline: 2.4523x; 1.2333x over previous
//
#include <hip/hip_runtime.h>
#include <hip/hip_bf16.h>

typedef __hip_bfloat16 bf16;
typedef short bf16x8 __attribute__((ext_vector_type(8)));
typedef float f32x4  __attribute__((ext_vector_type(4)));

static constexpr int D_IN  = 128;
static constexpr int D_H   = 256;
static constexpr int D_CAT = 768;

__device__ __forceinline__ float lrelu(float v){ return v > 0.f ? v : 0.2f*v; }
__device__ __forceinline__ float b2f(bf16 v){ return __bfloat162float(v); }
__device__ __forceinline__ bf16  f2b(float v){ return __float2bfloat16(v); }
__device__ __forceinline__ unsigned packb(float lo, float hi){
  bf16 a = f2b(lo), b = f2b(hi);
  unsigned short ua, ub;
  __builtin_memcpy(&ua, &a, 2); __builtin_memcpy(&ub, &b, 2);
  return (unsigned)ua | ((unsigned)ub << 16);
}

__device__ __forceinline__ void gload_lds16(const void* g, void* l){
  __builtin_amdgcn_global_load_lds(
      (const __attribute__((address_space(1))) unsigned*)g,
      (__attribute__((address_space(3))) unsigned*)l, 16, 0, 0);
}

// ================= CSR build =================
__global__ __launch_bounds__(256) void k_count(const int* __restrict__ col,
                                               int* __restrict__ cnt, int E){
  int e = blockIdx.x*256 + threadIdx.x;
  if (e < E) atomicAdd(&cnt[col[e]], 1);
}

__global__ __launch_bounds__(256) void k_scanA(const int* __restrict__ cnt,
                                               int* __restrict__ indptr,
                                               int* __restrict__ bsum, int N){
  __shared__ int s[256];
  int t = threadIdx.x, i = blockIdx.x*256 + t;
  int v = (i < N) ? cnt[i] : 0;
  s[t] = v; __syncthreads();
  #pragma unroll
  for (int d = 1; d < 256; d <<= 1){
    int tmp = (t >= d) ? s[t-d] : 0;
    __syncthreads();
    s[t] += tmp;
    __syncthreads();
  }
  if (i < N) indptr[i] = s[t] - v;
  if (t == 255) bsum[blockIdx.x] = s[255];
}

__global__ __launch_bounds__(256) void k_scanB(const int* __restrict__ bsum,
                                               int* __restrict__ boff,
                                               int* __restrict__ indptr,
                                               int nb, int N, int E){
  __shared__ int s[256];
  int t = threadIdx.x;
  int v = (t < nb) ? bsum[t] : 0;
  s[t] = v; __syncthreads();
  #pragma unroll
  for (int d = 1; d < 256; d <<= 1){
    int tmp = (t >= d) ? s[t-d] : 0;
    __syncthreads();
    s[t] += tmp;
    __syncthreads();
  }
  boff[t] = s[t] - v;
  if (t == 0) indptr[N] = E;
}

__global__ __launch_bounds__(256) void k_scanC(int* __restrict__ indptr,
                                               const int* __restrict__ boff, int N){
  int i = blockIdx.x*256 + threadIdx.x;
  if (i < N) indptr[i] += boff[blockIdx.x];
}

__global__ __launch_bounds__(256) void k_dis(const int* __restrict__ cnt,
                                             float* __restrict__ dis, int N){
  int i = blockIdx.x*256 + threadIdx.x;
  if (i < N) dis[i] = rsqrtf((float)cnt[i] + 1.0f);
}

__global__ __launch_bounds__(256) void k_fill(const int* __restrict__ row,
                                              const int* __restrict__ col,
                                              const int* __restrict__ indptr,
                                              int* __restrict__ cursor,
                                              int* __restrict__ esrc, int E){
  int e = blockIdx.x*256 + threadIdx.x;
  if (e < E){
    int c = col[e];
    int p = indptr[c] + atomicAdd(&cursor[c], 1);
    esrc[p] = row[e];
  }
}

// ================= prep =================
__global__ __launch_bounds__(256) void k_cast(const float* __restrict__ x,
                                              bf16* __restrict__ xb, int n4){
  int i = blockIdx.x*256 + threadIdx.x;
  if (i < n4){
    float4 v = reinterpret_cast<const float4*>(x)[i];
    bf16* o = xb + (size_t)i*4;
    o[0]=f2b(v.x); o[1]=f2b(v.y); o[2]=f2b(v.z); o[3]=f2b(v.w);
  }
}

// w_src = W_gat @ att_src, w_dst = W_gat @ att_dst  (each [128])
__global__ __launch_bounds__(128) void k_wvec(const float* __restrict__ W_gat,
                                              const float* __restrict__ att_src,
                                              const float* __restrict__ att_dst,
                                              float* __restrict__ wsrc,
                                              float* __restrict__ wdst){
  int k = threadIdx.x;
  float s1 = 0.f, s2 = 0.f;
  for (int j = 0; j < D_H; ++j){
    float w = W_gat[(size_t)k*D_H + j];
    s1 = fmaf(w, att_src[j], s1);
    s2 = fmaf(w, att_dst[j], s2);
  }
  wsrc[k] = s1; wdst[k] = s2;
}

// Bt_a [512][256]: cols 0-255 <- W_gcn (k<128), cols 256-511 <- W_gat (k>=128)
__global__ __launch_bounds__(256) void k_packA(const float* __restrict__ Wg,
                                               const float* __restrict__ Wa,
                                               bf16* __restrict__ Bt){
  int n = blockIdx.x, k = threadIdx.x;
  float v = 0.f;
  if (n < 256){ if (k < 128)  v = Wg[(size_t)k*D_H + n]; }
  else        { if (k >= 128) v = Wa[(size_t)(k-128)*D_H + (n-256)]; }
  Bt[(size_t)n*256 + k] = f2b(v);
}

// Bt_b [256][256]: k<128 -> W_sage_l, k>=128 -> W_sage_r
__global__ __launch_bounds__(256) void k_packB(const float* __restrict__ Wl,
                                               const float* __restrict__ Wr,
                                               bf16* __restrict__ Bt){
  int n = blockIdx.x, k = threadIdx.x;
  float v = (k < 128) ? Wl[(size_t)k*D_H + n] : Wr[(size_t)(k-128)*D_H + n];
  Bt[(size_t)n*256 + k] = f2b(v);
}

// BtF [256][768] <- W_fus [768][256]
__global__ __launch_bounds__(256) void k_packF(const float* __restrict__ W,
                                               bf16* __restrict__ Bt){
  int n = blockIdx.x;
  for (int k = threadIdx.x; k < D_CAT; k += 256)
    Bt[(size_t)n*D_CAT + k] = f2b(W[(size_t)k*D_H + n]);
}

__global__ __launch_bounds__(256) void k_bias2(const float* __restrict__ bg,
                                               const float* __restrict__ ba,
                                               float* __restrict__ out){
  int i = blockIdx.x*256 + threadIdx.x;
  if (i < 512) out[i] = (i < 256) ? bg[i] : ba[i-256];
}

// a_src/a_dst = xb @ wsrc/wdst  (one wave per node)
__global__ __launch_bounds__(256) void k_asrc(const bf16* __restrict__ xb,
                                              const float* __restrict__ wsrc,
                                              const float* __restrict__ wdst,
                                              float* __restrict__ a_src,
                                              float* __restrict__ a_dst, int N){
  int w = threadIdx.x >> 6, l = threadIdx.x & 63;
  int c = blockIdx.x*4 + w;
  if (c >= N) return;
  unsigned u = *(const unsigned*)(xb + (size_t)c*D_IN + 2*l);
  float x0 = __uint_as_float(u << 16);
  float x1 = __uint_as_float(u & 0xffff0000u);
  float s1 = x0*wsrc[2*l] + x1*wsrc[2*l+1];
  float s2 = x0*wdst[2*l] + x1*wdst[2*l+1];
  #pragma unroll
  for (int o = 32; o > 0; o >>= 1){
    s1 += __shfl_down(s1, o);
    s2 += __shfl_down(s2, o);
  }
  if (l == 0){ a_src[c] = s1; a_dst[c] = s2; }
}

// ================= x-space fused aggregation =================
// AGG row layout [512]: [0:128) dc*(sum dis_s*x_s + dc*x_c)
//                       [128:256) (sum pe*x_s + p0*x_c)/z
//                       [256:384) mean_s x_s
//                       [384:512) x_c  (copy for SAGE root GEMM)
__global__ __launch_bounds__(256) void k_aggx(
    const int* __restrict__ indptr, const int* __restrict__ esrc,
    const bf16* __restrict__ xb,
    const float* __restrict__ a_src, const float* __restrict__ a_dst,
    const float* __restrict__ dis,
    bf16* __restrict__ AGG, int N)
{
  int c = blockIdx.x;
  if (c >= N) return;
  int t = threadIdx.x;
  int beg = indptr[c], end = indptr[c+1];
  int deg = end - beg;
  float adst = a_dst[c], dc = dis[c];
  float eself = lrelu(a_src[c] + adst);

  __shared__ int   s_src[256];
  __shared__ float s_pe[256];
  __shared__ float s_ds[256];
  __shared__ float pg[4][128], pa[4][128], ps[4][128];
  __shared__ float red[4];

  // parallel max over incoming edges
  float lm = eself;
  for (int e = beg + t; e < end; e += 256)
    lm = fmaxf(lm, lrelu(a_src[esrc[e]] + adst));
  #pragma unroll
  for (int o = 32; o > 0; o >>= 1) lm = fmaxf(lm, __shfl_down(lm, o));
  if ((t & 63) == 0) red[t >> 6] = lm;
  __syncthreads();
  float m = fmaxf(fmaxf(red[0], red[1]), fmaxf(red[2], red[3]));

  float p0 = __expf(eself - m);
  float z_loc = (t == 0) ? p0 : 0.f;

  int d2 = t & 63;   // dims 2*d2, 2*d2+1
  int g  = t >> 6;   // edge group 0..3
  float g0=0.f,g1=0.f,a0=0.f,a1=0.f,sg0=0.f,sg1=0.f;

  for (int ch0 = beg; ch0 < end; ch0 += 256){
    int n = min(256, end - ch0);
    __syncthreads();
    if (t < n){
      int s = esrc[ch0 + t];
      float pe = __expf(lrelu(a_src[s] + adst) - m);
      s_src[t] = s; s_pe[t] = pe; s_ds[t] = dis[s];
      z_loc += pe;
    }
    __syncthreads();
    for (int i = g; i < n; i += 4){
      int s = s_src[i];
      float pe = s_pe[i], ds = s_ds[i];
      unsigned u = *(const unsigned*)(xb + (size_t)s*D_IN + 2*d2);
      float x0 = __uint_as_float(u << 16);
      float x1 = __uint_as_float(u & 0xffff0000u);
      g0 = fmaf(ds, x0, g0); g1 = fmaf(ds, x1, g1);
      a0 = fmaf(pe, x0, a0); a1 = fmaf(pe, x1, a1);
      sg0 += x0; sg1 += x1;
    }
  }

  // z reduction
  #pragma unroll
  for (int o = 32; o > 0; o >>= 1) z_loc += __shfl_down(z_loc, o);
  __syncthreads();
  if ((t & 63) == 0) red[t >> 6] = z_loc;
  __syncthreads();
  float z = red[0] + red[1] + red[2] + red[3];

  // cross-group reduce via LDS
  pg[g][2*d2] = g0; pg[g][2*d2+1] = g1;
  pa[g][2*d2] = a0; pa[g][2*d2+1] = a1;
  ps[g][2*d2] = sg0; ps[g][2*d2+1] = sg1;
  __syncthreads();

  if (t < 64){
    int d0 = 2*t, d1 = 2*t + 1;
    float G0 = pg[0][d0]+pg[1][d0]+pg[2][d0]+pg[3][d0];
    float G1 = pg[0][d1]+pg[1][d1]+pg[2][d1]+pg[3][d1];
    float A0 = pa[0][d0]+pa[1][d0]+pa[2][d0]+pa[3][d0];
    float A1 = pa[0][d1]+pa[1][d1]+pa[2][d1]+pa[3][d1];
    float S0 = ps[0][d0]+ps[1][d0]+ps[2][d0]+ps[3][d0];
    float S1 = ps[0][d1]+ps[1][d1]+ps[2][d1]+ps[3][d1];
    unsigned xu = *(const unsigned*)(xb + (size_t)c*D_IN + d0);
    float xc0 = __uint_as_float(xu << 16);
    float xc1 = __uint_as_float(xu & 0xffff0000u);
    float invz = 1.f / (z + 1e-16f);
    float invc = 1.f / fmaxf((float)deg, 1.f);
    unsigned* rowp = (unsigned*)(AGG + (size_t)c*512);
    rowp[t]        = packb(dc*(G0 + dc*xc0), dc*(G1 + dc*xc1));
    rowp[64 + t]   = packb((A0 + p0*xc0)*invz, (A1 + p0*xc1)*invz);
    rowp[128 + t]  = packb(S0*invc, S1*invc);
    rowp[192 + t]  = xu;
  }
}

// ================= MFMA GEMM =================
// C[M,Ncols] = A[M,K]bf16 @ Bt[Ncols][K]bf16 + bias; 128x128 tile, BK=64.
template<bool RELU, bool OUTF32>
__global__ __launch_bounds__(256) void k_mfma(
    const bf16* __restrict__ A, int lda,
    const bf16* __restrict__ Bt,
    const float* __restrict__ bias,
    void* __restrict__ Cv, int ldc,
    int M, int K)
{
  __shared__ short As[128*64];
  __shared__ short Bs[128*64];
  int tid  = threadIdx.x;
  int bm   = blockIdx.y*128, bn = blockIdx.x*128;
  int wave = tid >> 6, lane = tid & 63;
  int wr   = (wave >> 1)*64, wc = (wave & 1)*64;
  int l15  = lane & 15, l4 = lane >> 4;

  f32x4 acc[4][4] = {};

  for (int k0 = 0; k0 < K; k0 += 64){
    #pragma unroll
    for (int i = 0; i < 4; ++i){
      int slot = i*256 + tid;
      int r = slot >> 3, gp = slot & 7;
      int gk = gp ^ (r & 7);
      int ra = bm + r; ra = (ra < M) ? ra : (M-1);
      gload_lds16(A  + (size_t)ra*lda + k0 + gk*8, As + (size_t)slot*8);
      gload_lds16(Bt + (size_t)(bn + r)*K + k0 + gk*8, Bs + (size_t)slot*8);
    }
    __syncthreads();

    #pragma unroll
    for (int kk = 0; kk < 2; ++kk){
      bf16x8 af[4], bfr[4];
      #pragma unroll
      for (int mi = 0; mi < 4; ++mi){
        int r = wr + mi*16 + l15;
        int gk = kk*4 + l4;
        af[mi] = *(const bf16x8*)(As + r*64 + ((gk ^ (r & 7))*8));
      }
      #pragma unroll
      for (int ni = 0; ni < 4; ++ni){
        int r = wc + ni*16 + l15;
        int gk = kk*4 + l4;
        bfr[ni] = *(const bf16x8*)(Bs + r*64 + ((gk ^ (r & 7))*8));
      }
      #pragma unroll
      for (int mi = 0; mi < 4; ++mi)
        #pragma unroll
        for (int ni = 0; ni < 4; ++ni)
          acc[mi][ni] = __builtin_amdgcn_mfma_f32_16x16x32_bf16(
                            af[mi], bfr[ni], acc[mi][ni], 0, 0, 0);
    }
    __syncthreads();
  }

  #pragma unroll
  for (int mi = 0; mi < 4; ++mi){
    #pragma unroll
    for (int r = 0; r < 4; ++r){
      int row = bm + wr + mi*16 + l4*4 + r;
      if (row >= M) continue;
      #pragma unroll
      for (int ni = 0; ni < 4; ++ni){
        int col = bn + wc + ni*16 + l15;
        float v = acc[mi][ni][r] + bias[col];
        if (RELU) v = fmaxf(v, 0.f);
        if (OUTF32) ((float*)Cv)[(size_t)row*ldc + col] = v;
        else        ((bf16*) Cv)[(size_t)row*ldc + col] = f2b(v);
      }
    }
  }
}

// ================= host =================
static inline char* carve(char*& p, size_t bytes){
  char* r = p;
  p += (bytes + 255) & ~(size_t)255;
  return r;
}

extern "C" void kernel_launch(void* const* d_in, const int* in_sizes, int n_in,
                              void* d_out, int out_size, void* d_ws, size_t ws_size,
                              hipStream_t stream) {
  const float* x        = (const float*)d_in[0];
  const int*   ei       = (const int*)  d_in[1];
  const float* W_gcn    = (const float*)d_in[2];
  const float* b_gcn    = (const float*)d_in[3];
  const float* W_gat    = (const float*)d_in[4];
  const float* att_src  = (const float*)d_in[5];
  const float* att_dst  = (const float*)d_in[6];
  const float* b_gat    = (const float*)d_in[7];
  const float* W_sage_l = (const float*)d_in[8];
  const float* b_sage_l = (const float*)d_in[9];
  const float* W_sage_r = (const float*)d_in[10];
  const float* W_fus    = (const float*)d_in[11];
  const float* b_fus    = (const float*)d_in[12];

  const int N = in_sizes[0] / D_IN;
  const int E = in_sizes[1] / 2;
  const int* erow = ei;
  const int* ecol = ei + E;

  char* p = (char*)d_ws;
  bf16*  AGG    = (bf16*) carve(p, (size_t)N*512*2);       // gcn'|gat'|mean|x
  bf16*  H      = (bf16*) carve(p, (size_t)N*D_CAT*2);
  bf16*  xb     = (bf16*) carve(p, (size_t)N*D_IN*2);
  bf16*  BtA    = (bf16*) carve(p, (size_t)512*256*2);
  bf16*  BtB    = (bf16*) carve(p, (size_t)256*256*2);
  bf16*  BtF    = (bf16*) carve(p, (size_t)256*D_CAT*2);
  float* bias_a = (float*)carve(p, 512*4);
  float* wsrc   = (float*)carve(p, D_IN*4);
  float* wdst   = (float*)carve(p, D_IN*4);
  float* a_src  = (float*)carve(p, (size_t)N*4);
  float* a_dst  = (float*)carve(p, (size_t)N*4);
  float* dis    = (float*)carve(p, (size_t)N*4);
  int*   cnt    = (int*)  carve(p, (size_t)N*4);
  int*   cursor = (int*)  carve(p, (size_t)N*4);
  int*   indptr = (int*)  carve(p, (size_t)(N+1)*4);
  int*   bsum   = (int*)  carve(p, 256*4);
  int*   boff   = (int*)  carve(p, 256*4);
  int*   esrc   = (int*)  carve(p, (size_t)E*4);
  (void)ws_size; (void)n_in; (void)out_size;

  hipMemsetAsync(cnt,    0, (size_t)N*4, stream);
  hipMemsetAsync(cursor, 0, (size_t)N*4, stream);

  const int nb = (N + 255) / 256;
  const int eb = (E + 255) / 256;

  // prep
  k_cast <<<(N*D_IN/4 + 255)/256, 256, 0, stream>>>(x, xb, N*D_IN/4);
  k_wvec <<<1, 128, 0, stream>>>(W_gat, att_src, att_dst, wsrc, wdst);
  k_packA<<<512, 256, 0, stream>>>(W_gcn, W_gat, BtA);
  k_packB<<<256, 256, 0, stream>>>(W_sage_l, W_sage_r, BtB);
  k_packF<<<256, 256, 0, stream>>>(W_fus, BtF);
  k_bias2<<<2, 256, 0, stream>>>(b_gcn, b_gat, bias_a);

  // CSR
  k_count<<<eb, 256, 0, stream>>>(ecol, cnt, E);
  k_scanA<<<nb, 256, 0, stream>>>(cnt, indptr, bsum, N);
  k_scanB<<<1, 256, 0, stream>>>(bsum, boff, indptr, nb, N, E);
  k_scanC<<<nb, 256, 0, stream>>>(indptr, boff, N);
  k_dis  <<<nb, 256, 0, stream>>>(cnt, dis, N);
  k_fill <<<eb, 256, 0, stream>>>(erow, ecol, indptr, cursor, esrc, E);

  // attention logits (GEMV with folded weight vectors)
  k_asrc<<<(N + 3)/4, 256, 0, stream>>>(xb, wsrc, wdst, a_src, a_dst, N);

  // x-space aggregation
  k_aggx<<<N, 256, 0, stream>>>(indptr, esrc, xb, a_src, a_dst, dis, AGG, N);

  const int mtiles = (N + 127) / 128;

  // H[:,0:512] = relu([agg_gcn'|agg_gat'] @ blockdiag(W_gcn,W_gat) + [b_gcn|b_gat])
  k_mfma<true, false><<<dim3(4, mtiles), 256, 0, stream>>>(
      AGG, 512, BtA, bias_a, H, D_CAT, N, 256);

  // H[:,512:768] = relu([mean|x] @ [W_sage_l;W_sage_r] + b_sage_l)
  k_mfma<true, false><<<dim3(2, mtiles), 256, 0, stream>>>(
      AGG + 256, 512, BtB, b_sage_l, H + 512, D_CAT, N, 256);

  // out = H @ W_fus + b_fus (fp32)
  k_mfma<false, true><<<dim3(2, mtiles), 256, 0, stream>>>(
      H, D_CAT, BtF, b_fus, (float*)d_out, D_H, N, D_CAT);
}

// Round 8
// 374.953 us; speedup vs baseline: 2.7698x; 1.1294x over previous
//
#include <hip/hip_runtime.h>
#include <hip/hip_bf16.h>

typedef __hip_bfloat16 bf16;
typedef short bf16x8 __attribute__((ext_vector_type(8)));
typedef float f32x4  __attribute__((ext_vector_type(4)));

static constexpr int D_IN  = 128;
static constexpr int D_H   = 256;
static constexpr int D_CAT = 768;

__device__ __forceinline__ float lrelu(float v){ return v > 0.f ? v : 0.2f*v; }
__device__ __forceinline__ float b2f(bf16 v){ return __bfloat162float(v); }
__device__ __forceinline__ bf16  f2b(float v){ return __float2bfloat16(v); }
__device__ __forceinline__ unsigned packb(float lo, float hi){
  bf16 a = f2b(lo), b = f2b(hi);
  unsigned short ua, ub;
  __builtin_memcpy(&ua, &a, 2); __builtin_memcpy(&ub, &b, 2);
  return (unsigned)ua | ((unsigned)ub << 16);
}
__device__ __forceinline__ short bbits(float v){
  bf16 h = f2b(v); short s; __builtin_memcpy(&s, &h, 2); return s;
}

__device__ __forceinline__ void gload_lds16(const void* g, void* l){
  __builtin_amdgcn_global_load_lds(
      (const __attribute__((address_space(1))) unsigned*)g,
      (__attribute__((address_space(3))) unsigned*)l, 16, 0, 0);
}

// ================= CSR build =================
__global__ __launch_bounds__(256) void k_count(const int* __restrict__ col,
                                               int* __restrict__ cnt, int E){
  int e = blockIdx.x*256 + threadIdx.x;
  if (e < E) atomicAdd(&cnt[col[e]], 1);
}

__global__ __launch_bounds__(256) void k_scanA(const int* __restrict__ cnt,
                                               int* __restrict__ indptr,
                                               int* __restrict__ bsum, int N){
  __shared__ int s[256];
  int t = threadIdx.x, i = blockIdx.x*256 + t;
  int v = (i < N) ? cnt[i] : 0;
  s[t] = v; __syncthreads();
  #pragma unroll
  for (int d = 1; d < 256; d <<= 1){
    int tmp = (t >= d) ? s[t-d] : 0;
    __syncthreads();
    s[t] += tmp;
    __syncthreads();
  }
  if (i < N) indptr[i] = s[t] - v;
  if (t == 255) bsum[blockIdx.x] = s[255];
}

__global__ __launch_bounds__(256) void k_scanB(const int* __restrict__ bsum,
                                               int* __restrict__ boff,
                                               int* __restrict__ indptr,
                                               int nb, int N, int E){
  __shared__ int s[256];
  int t = threadIdx.x;
  int v = (t < nb) ? bsum[t] : 0;
  s[t] = v; __syncthreads();
  #pragma unroll
  for (int d = 1; d < 256; d <<= 1){
    int tmp = (t >= d) ? s[t-d] : 0;
    __syncthreads();
    s[t] += tmp;
    __syncthreads();
  }
  boff[t] = s[t] - v;
  if (t == 0) indptr[N] = E;
}

__global__ __launch_bounds__(256) void k_scanC(int* __restrict__ indptr,
                                               const int* __restrict__ boff, int N){
  int i = blockIdx.x*256 + threadIdx.x;
  if (i < N) indptr[i] += boff[blockIdx.x];
}

__global__ __launch_bounds__(256) void k_dis(const int* __restrict__ cnt,
                                             float* __restrict__ dis, int N){
  int i = blockIdx.x*256 + threadIdx.x;
  if (i < N) dis[i] = rsqrtf((float)cnt[i] + 1.0f);
}

__global__ __launch_bounds__(256) void k_fill(const int* __restrict__ row,
                                              const int* __restrict__ col,
                                              const int* __restrict__ indptr,
                                              int* __restrict__ cursor,
                                              int* __restrict__ esrc, int E){
  int e = blockIdx.x*256 + threadIdx.x;
  if (e < E){
    int c = col[e];
    int p = indptr[c] + atomicAdd(&cursor[c], 1);
    esrc[p] = row[e];
  }
}

// ================= prep =================
__global__ __launch_bounds__(256) void k_cast(const float* __restrict__ x,
                                              bf16* __restrict__ xb, int n4){
  int i = blockIdx.x*256 + threadIdx.x;
  if (i < n4){
    float4 v = reinterpret_cast<const float4*>(x)[i];
    bf16* o = xb + (size_t)i*4;
    o[0]=f2b(v.x); o[1]=f2b(v.y); o[2]=f2b(v.z); o[3]=f2b(v.w);
  }
}

// w_src = W_gat @ att_src, w_dst = W_gat @ att_dst  (each [128])
__global__ __launch_bounds__(128) void k_wvec(const float* __restrict__ W_gat,
                                              const float* __restrict__ att_src,
                                              const float* __restrict__ att_dst,
                                              float* __restrict__ wsrc,
                                              float* __restrict__ wdst){
  int k = threadIdx.x;
  float s1 = 0.f, s2 = 0.f;
  for (int j = 0; j < D_H; ++j){
    float w = W_gat[(size_t)k*D_H + j];
    s1 = fmaf(w, att_src[j], s1);
    s2 = fmaf(w, att_dst[j], s2);
  }
  wsrc[k] = s1; wdst[k] = s2;
}

// W1t [768][256]: row n = H col, col k over the matching AGG-col block.
// n<256 (gcn):  k<128 -> W_gcn[k][n],        else 0
// n<512 (gat):  k>=128 -> W_gat[k-128][n-256], else 0
// n<768 (sage): k<128 -> W_sage_l[k][n-512], k>=128 -> W_sage_r[k-128][n-512]
__global__ __launch_bounds__(256) void k_packW1(const float* __restrict__ Wg,
                                                const float* __restrict__ Wa,
                                                const float* __restrict__ Wl,
                                                const float* __restrict__ Wr,
                                                bf16* __restrict__ W1t){
  int n = blockIdx.x, k = threadIdx.x;
  float v = 0.f;
  if (n < 256)      { if (k < 128)  v = Wg[(size_t)k*D_H + n]; }
  else if (n < 512) { if (k >= 128) v = Wa[(size_t)(k-128)*D_H + (n-256)]; }
  else              { v = (k < 128) ? Wl[(size_t)k*D_H + (n-512)]
                                    : Wr[(size_t)(k-128)*D_H + (n-512)]; }
  W1t[(size_t)n*256 + k] = f2b(v);
}

// W2t [256][768] <- W_fus [768][256]
__global__ __launch_bounds__(256) void k_packF(const float* __restrict__ W,
                                               bf16* __restrict__ Bt){
  int n = blockIdx.x;
  for (int k = threadIdx.x; k < D_CAT; k += 256)
    Bt[(size_t)n*D_CAT + k] = f2b(W[(size_t)k*D_H + n]);
}

__global__ __launch_bounds__(256) void k_bias3(const float* __restrict__ bg,
                                               const float* __restrict__ ba,
                                               const float* __restrict__ bs,
                                               float* __restrict__ out){
  int i = blockIdx.x*256 + threadIdx.x;
  if (i < 256)      out[i] = bg[i];
  else if (i < 512) out[i] = ba[i-256];
  else if (i < 768) out[i] = bs[i-512];
}

// a_src/a_dst = xb @ wsrc/wdst  (one wave per node)
__global__ __launch_bounds__(256) void k_asrc(const bf16* __restrict__ xb,
                                              const float* __restrict__ wsrc,
                                              const float* __restrict__ wdst,
                                              float* __restrict__ a_src,
                                              float* __restrict__ a_dst, int N){
  int w = threadIdx.x >> 6, l = threadIdx.x & 63;
  int c = blockIdx.x*4 + w;
  if (c >= N) return;
  unsigned u = *(const unsigned*)(xb + (size_t)c*D_IN + 2*l);
  float x0 = __uint_as_float(u << 16);
  float x1 = __uint_as_float(u & 0xffff0000u);
  float s1 = x0*wsrc[2*l] + x1*wsrc[2*l+1];
  float s2 = x0*wdst[2*l] + x1*wdst[2*l+1];
  #pragma unroll
  for (int o = 32; o > 0; o >>= 1){
    s1 += __shfl_down(s1, o);
    s2 += __shfl_down(s2, o);
  }
  if (l == 0){ a_src[c] = s1; a_dst[c] = s2; }
}

// ================= x-space fused aggregation =================
// AGG row [512]: [0:128) gcn'  [128:256) gat'  [256:384) mean  [384:512) x
__global__ __launch_bounds__(256) void k_aggx(
    const int* __restrict__ indptr, const int* __restrict__ esrc,
    const bf16* __restrict__ xb,
    const float* __restrict__ a_src, const float* __restrict__ a_dst,
    const float* __restrict__ dis,
    bf16* __restrict__ AGG, int N)
{
  int c = blockIdx.x;
  if (c >= N) return;
  int t = threadIdx.x;
  int beg = indptr[c], end = indptr[c+1];
  int deg = end - beg;
  float adst = a_dst[c], dc = dis[c];
  float eself = lrelu(a_src[c] + adst);

  __shared__ int   s_src[256];
  __shared__ float s_pe[256];
  __shared__ float s_ds[256];
  __shared__ float pg[4][128], pa[4][128], ps[4][128];
  __shared__ float red[4];

  // parallel max over incoming edges
  float lm = eself;
  for (int e = beg + t; e < end; e += 256)
    lm = fmaxf(lm, lrelu(a_src[esrc[e]] + adst));
  #pragma unroll
  for (int o = 32; o > 0; o >>= 1) lm = fmaxf(lm, __shfl_down(lm, o));
  if ((t & 63) == 0) red[t >> 6] = lm;
  __syncthreads();
  float m = fmaxf(fmaxf(red[0], red[1]), fmaxf(red[2], red[3]));

  float p0 = __expf(eself - m);
  float z_loc = (t == 0) ? p0 : 0.f;

  int d2 = t & 63;   // dims 2*d2, 2*d2+1
  int g  = t >> 6;   // edge group 0..3
  float g0=0.f,g1=0.f,a0=0.f,a1=0.f,sg0=0.f,sg1=0.f;

  for (int ch0 = beg; ch0 < end; ch0 += 256){
    int n = min(256, end - ch0);
    __syncthreads();
    if (t < n){
      int s = esrc[ch0 + t];
      float pe = __expf(lrelu(a_src[s] + adst) - m);
      s_src[t] = s; s_pe[t] = pe; s_ds[t] = dis[s];
      z_loc += pe;
    }
    __syncthreads();
    int i = g;
    // 4-wide unroll: 4 independent gathers in flight per group
    for (; i + 12 < n; i += 16){
      int sA = s_src[i],    sB = s_src[i+4],
          sC = s_src[i+8],  sD = s_src[i+12];
      unsigned uA = *(const unsigned*)(xb + (size_t)sA*D_IN + 2*d2);
      unsigned uB = *(const unsigned*)(xb + (size_t)sB*D_IN + 2*d2);
      unsigned uC = *(const unsigned*)(xb + (size_t)sC*D_IN + 2*d2);
      unsigned uD = *(const unsigned*)(xb + (size_t)sD*D_IN + 2*d2);
      float peA = s_pe[i],   dsA = s_ds[i];
      float peB = s_pe[i+4], dsB = s_ds[i+4];
      float peC = s_pe[i+8], dsC = s_ds[i+8];
      float peD = s_pe[i+12],dsD = s_ds[i+12];
      float xA0 = __uint_as_float(uA << 16), xA1 = __uint_as_float(uA & 0xffff0000u);
      float xB0 = __uint_as_float(uB << 16), xB1 = __uint_as_float(uB & 0xffff0000u);
      float xC0 = __uint_as_float(uC << 16), xC1 = __uint_as_float(uC & 0xffff0000u);
      float xD0 = __uint_as_float(uD << 16), xD1 = __uint_as_float(uD & 0xffff0000u);
      g0 = fmaf(dsA,xA0,g0); g1 = fmaf(dsA,xA1,g1);
      a0 = fmaf(peA,xA0,a0); a1 = fmaf(peA,xA1,a1);
      sg0 += xA0; sg1 += xA1;
      g0 = fmaf(dsB,xB0,g0); g1 = fmaf(dsB,xB1,g1);
      a0 = fmaf(peB,xB0,a0); a1 = fmaf(peB,xB1,a1);
      sg0 += xB0; sg1 += xB1;
      g0 = fmaf(dsC,xC0,g0); g1 = fmaf(dsC,xC1,g1);
      a0 = fmaf(peC,xC0,a0); a1 = fmaf(peC,xC1,a1);
      sg0 += xC0; sg1 += xC1;
      g0 = fmaf(dsD,xD0,g0); g1 = fmaf(dsD,xD1,g1);
      a0 = fmaf(peD,xD0,a0); a1 = fmaf(peD,xD1,a1);
      sg0 += xD0; sg1 += xD1;
    }
    for (; i < n; i += 4){
      int s = s_src[i];
      float pe = s_pe[i], ds = s_ds[i];
      unsigned u = *(const unsigned*)(xb + (size_t)s*D_IN + 2*d2);
      float x0 = __uint_as_float(u << 16);
      float x1 = __uint_as_float(u & 0xffff0000u);
      g0 = fmaf(ds, x0, g0); g1 = fmaf(ds, x1, g1);
      a0 = fmaf(pe, x0, a0); a1 = fmaf(pe, x1, a1);
      sg0 += x0; sg1 += x1;
    }
  }

  // z reduction
  #pragma unroll
  for (int o = 32; o > 0; o >>= 1) z_loc += __shfl_down(z_loc, o);
  __syncthreads();
  if ((t & 63) == 0) red[t >> 6] = z_loc;
  __syncthreads();
  float z = red[0] + red[1] + red[2] + red[3];

  // cross-group reduce via LDS
  pg[g][2*d2] = g0; pg[g][2*d2+1] = g1;
  pa[g][2*d2] = a0; pa[g][2*d2+1] = a1;
  ps[g][2*d2] = sg0; ps[g][2*d2+1] = sg1;
  __syncthreads();

  if (t < 64){
    int d0 = 2*t, d1 = 2*t + 1;
    float G0 = pg[0][d0]+pg[1][d0]+pg[2][d0]+pg[3][d0];
    float G1 = pg[0][d1]+pg[1][d1]+pg[2][d1]+pg[3][d1];
    float A0 = pa[0][d0]+pa[1][d0]+pa[2][d0]+pa[3][d0];
    float A1 = pa[0][d1]+pa[1][d1]+pa[2][d1]+pa[3][d1];
    float S0 = ps[0][d0]+ps[1][d0]+ps[2][d0]+ps[3][d0];
    float S1 = ps[0][d1]+ps[1][d1]+ps[2][d1]+ps[3][d1];
    unsigned xu = *(const unsigned*)(xb + (size_t)c*D_IN + d0);
    float xc0 = __uint_as_float(xu << 16);
    float xc1 = __uint_as_float(xu & 0xffff0000u);
    float invz = 1.f / (z + 1e-16f);
    float invc = 1.f / fmaxf((float)deg, 1.f);
    unsigned* rowp = (unsigned*)(AGG + (size_t)c*512);
    rowp[t]        = packb(dc*(G0 + dc*xc0), dc*(G1 + dc*xc1));
    rowp[64 + t]   = packb((A0 + p0*xc0)*invz, (A1 + p0*xc1)*invz);
    rowp[128 + t]  = packb(S0*invc, S1*invc);
    rowp[192 + t]  = xu;
  }
}

// ================= fused MLP: out = relu(AGG@W1 + b1) @ W_fus + b_fus ======
// 64-row tile, 512 threads (8 waves), LDS 80KB -> 2 blocks/CU.
// Stage 1 per 128-col H chunk j (panel-skips structural zeros), Hc in LDS bf16;
// Stage 2 accumulates out (fp32 frags) across the 6 chunks. H never hits HBM.
__global__ __launch_bounds__(512, 4) void k_mlp(
    const bf16* __restrict__ AGG,   // [M][512]
    const bf16* __restrict__ W1t,   // [768][256]
    const bf16* __restrict__ W2t,   // [256][768]
    const float* __restrict__ bias1,// [768]
    const float* __restrict__ bias2,// [256]
    float* __restrict__ out, int M)
{
  __shared__ short A_res[4*64*64];   // 32KB: 4 K-panels of [64][64], swizzled
  __shared__ short Hc[2*64*64];      // 16KB: 2 K-panels
  __shared__ short SW[256*64];       // 32KB: stage-1 Bs (first 8K) / stage-2 W2s
  int tid  = threadIdx.x;
  int bm   = blockIdx.x*64;
  int wave = tid >> 6, lane = tid & 63;
  int l15  = lane & 15, l4 = lane >> 4;
  int wr   = (wave >> 2)*32;   // 0 / 32
  int wcol = wave & 3;         // 0..3

  f32x4 oacc[2][4] = {};

  // resident A: part 0 (AGG cols 0..255)
  #pragma unroll
  for (int i = 0; i < 4; ++i){
    int slot = i*512 + tid;
    int rr = (slot >> 3) & 63, gp = slot & 7;
    int gk = gp ^ (rr & 7);
    int p  = slot >> 9;
    int row = bm + rr; if (row >= M) row = M - 1;
    gload_lds16(AGG + (size_t)row*512 + p*64 + gk*8, A_res + (size_t)slot*8);
  }

  #pragma unroll
  for (int j = 0; j < 6; ++j){
    if (j == 4){
      // swap resident A to part 1 (AGG cols 256..511)
      #pragma unroll
      for (int i = 0; i < 4; ++i){
        int slot = i*512 + tid;
        int rr = (slot >> 3) & 63, gp = slot & 7;
        int gk = gp ^ (rr & 7);
        int p  = slot >> 9;
        int row = bm + rr; if (row >= M) row = M - 1;
        gload_lds16(AGG + (size_t)row*512 + 256 + p*64 + gk*8, A_res + (size_t)slot*8);
      }
    }
    // ---- stage 1: Hc = relu(A @ W1[,chunk j] + b1) ----
    const int p0 = (j < 2) ? 0 : ((j < 4) ? 2 : 0);
    const int np = (j < 4) ? 2 : 4;
    f32x4 hacc[2][2] = {};
    for (int pp = 0; pp < np; ++pp){
      int p = p0 + pp;
      __syncthreads();
      #pragma unroll
      for (int i = 0; i < 2; ++i){
        int slot = i*512 + tid;
        int r = slot >> 3, gp = slot & 7;
        int gk = gp ^ (r & 7);
        gload_lds16(W1t + (size_t)(j*128 + r)*256 + p*64 + gk*8, SW + (size_t)slot*8);
      }
      __syncthreads();
      #pragma unroll
      for (int kk = 0; kk < 2; ++kk){
        bf16x8 af[2], bfv[2];
        #pragma unroll
        for (int mi = 0; mi < 2; ++mi){
          int r = wr + mi*16 + l15;
          int gk = kk*4 + l4;
          af[mi] = *(const bf16x8*)(A_res + p*4096 + r*64 + ((gk ^ (r & 7))*8));
        }
        #pragma unroll
        for (int ni = 0; ni < 2; ++ni){
          int r = wcol*32 + ni*16 + l15;
          int gk = kk*4 + l4;
          bfv[ni] = *(const bf16x8*)(SW + r*64 + ((gk ^ (r & 7))*8));
        }
        #pragma unroll
        for (int mi = 0; mi < 2; ++mi)
          #pragma unroll
          for (int ni = 0; ni < 2; ++ni)
            hacc[mi][ni] = __builtin_amdgcn_mfma_f32_16x16x32_bf16(
                               af[mi], bfv[ni], hacc[mi][ni], 0, 0, 0);
      }
    }
    // write Hc (relu + bias, bf16, swizzled panels)
    #pragma unroll
    for (int mi = 0; mi < 2; ++mi)
      #pragma unroll
      for (int ni = 0; ni < 2; ++ni){
        int cc = wcol*32 + ni*16 + l15;
        float bb = bias1[j*128 + cc];
        int q = cc >> 6, g8 = (cc >> 3) & 7, e = cc & 7;
        #pragma unroll
        for (int r = 0; r < 4; ++r){
          int rr = wr + mi*16 + l4*4 + r;
          float v = fmaxf(hacc[mi][ni][r] + bb, 0.f);
          Hc[q*4096 + rr*64 + ((g8 ^ (rr & 7))*8) + e] = bbits(v);
        }
      }
    // ---- stage 2: oacc += Hc @ W_fus[chunk j rows] ----
    #pragma unroll
    for (int q = 0; q < 2; ++q){
      __syncthreads();   // Hc visible; SW free
      #pragma unroll
      for (int i = 0; i < 4; ++i){
        int slot = i*512 + tid;
        int r = slot >> 3, gp = slot & 7;
        int gk = gp ^ (r & 7);
        gload_lds16(W2t + (size_t)r*768 + j*128 + q*64 + gk*8, SW + (size_t)slot*8);
      }
      __syncthreads();
      #pragma unroll
      for (int kk = 0; kk < 2; ++kk){
        bf16x8 af[2], bfv[4];
        #pragma unroll
        for (int mi = 0; mi < 2; ++mi){
          int r = wr + mi*16 + l15;
          int gk = kk*4 + l4;
          af[mi] = *(const bf16x8*)(Hc + q*4096 + r*64 + ((gk ^ (r & 7))*8));
        }
        #pragma unroll
        for (int ni = 0; ni < 4; ++ni){
          int r = wcol*64 + ni*16 + l15;
          int gk = kk*4 + l4;
          bfv[ni] = *(const bf16x8*)(SW + r*64 + ((gk ^ (r & 7))*8));
        }
        #pragma unroll
        for (int mi = 0; mi < 2; ++mi)
          #pragma unroll
          for (int ni = 0; ni < 4; ++ni)
            oacc[mi][ni] = __builtin_amdgcn_mfma_f32_16x16x32_bf16(
                               af[mi], bfv[ni], oacc[mi][ni], 0, 0, 0);
      }
    }
  }

  // epilogue
  #pragma unroll
  for (int mi = 0; mi < 2; ++mi)
    #pragma unroll
    for (int r = 0; r < 4; ++r){
      int row = bm + wr + mi*16 + l4*4 + r;
      if (row >= M) continue;
      #pragma unroll
      for (int ni = 0; ni < 4; ++ni){
        int col = wcol*64 + ni*16 + l15;
        out[(size_t)row*256 + col] = oacc[mi][ni][r] + bias2[col];
      }
    }
}

// ================= host =================
static inline char* carve(char*& p, size_t bytes){
  char* r = p;
  p += (bytes + 255) & ~(size_t)255;
  return r;
}

extern "C" void kernel_launch(void* const* d_in, const int* in_sizes, int n_in,
                              void* d_out, int out_size, void* d_ws, size_t ws_size,
                              hipStream_t stream) {
  const float* x        = (const float*)d_in[0];
  const int*   ei       = (const int*)  d_in[1];
  const float* W_gcn    = (const float*)d_in[2];
  const float* b_gcn    = (const float*)d_in[3];
  const float* W_gat    = (const float*)d_in[4];
  const float* att_src  = (const float*)d_in[5];
  const float* att_dst  = (const float*)d_in[6];
  const float* b_gat    = (const float*)d_in[7];
  const float* W_sage_l = (const float*)d_in[8];
  const float* b_sage_l = (const float*)d_in[9];
  const float* W_sage_r = (const float*)d_in[10];
  const float* W_fus    = (const float*)d_in[11];
  const float* b_fus    = (const float*)d_in[12];

  const int N = in_sizes[0] / D_IN;
  const int E = in_sizes[1] / 2;
  const int* erow = ei;
  const int* ecol = ei + E;

  char* p = (char*)d_ws;
  bf16*  AGG    = (bf16*) carve(p, (size_t)N*512*2);     // gcn'|gat'|mean|x
  bf16*  xb     = (bf16*) carve(p, (size_t)N*D_IN*2);
  bf16*  W1t    = (bf16*) carve(p, (size_t)D_CAT*256*2);
  bf16*  W2t    = (bf16*) carve(p, (size_t)256*D_CAT*2);
  float* bias1  = (float*)carve(p, D_CAT*4);
  float* wsrc   = (float*)carve(p, D_IN*4);
  float* wdst   = (float*)carve(p, D_IN*4);
  float* a_src  = (float*)carve(p, (size_t)N*4);
  float* a_dst  = (float*)carve(p, (size_t)N*4);
  float* dis    = (float*)carve(p, (size_t)N*4);
  int*   cnt    = (int*)  carve(p, (size_t)N*4);
  int*   cursor = (int*)  carve(p, (size_t)N*4);
  int*   indptr = (int*)  carve(p, (size_t)(N+1)*4);
  int*   bsum   = (int*)  carve(p, 256*4);
  int*   boff   = (int*)  carve(p, 256*4);
  int*   esrc   = (int*)  carve(p, (size_t)E*4);
  (void)ws_size; (void)n_in; (void)out_size;

  hipMemsetAsync(cnt,    0, (size_t)N*4, stream);
  hipMemsetAsync(cursor, 0, (size_t)N*4, stream);

  const int nb = (N + 255) / 256;
  const int eb = (E + 255) / 256;

  // prep
  k_cast  <<<(N*D_IN/4 + 255)/256, 256, 0, stream>>>(x, xb, N*D_IN/4);
  k_wvec  <<<1, 128, 0, stream>>>(W_gat, att_src, att_dst, wsrc, wdst);
  k_packW1<<<D_CAT, 256, 0, stream>>>(W_gcn, W_gat, W_sage_l, W_sage_r, W1t);
  k_packF <<<256, 256, 0, stream>>>(W_fus, W2t);
  k_bias3 <<<3, 256, 0, stream>>>(b_gcn, b_gat, b_sage_l, bias1);

  // CSR
  k_count<<<eb, 256, 0, stream>>>(ecol, cnt, E);
  k_scanA<<<nb, 256, 0, stream>>>(cnt, indptr, bsum, N);
  k_scanB<<<1, 256, 0, stream>>>(bsum, boff, indptr, nb, N, E);
  k_scanC<<<nb, 256, 0, stream>>>(indptr, boff, N);
  k_dis  <<<nb, 256, 0, stream>>>(cnt, dis, N);
  k_fill <<<eb, 256, 0, stream>>>(erow, ecol, indptr, cursor, esrc, E);

  // attention logits
  k_asrc<<<(N + 3)/4, 256, 0, stream>>>(xb, wsrc, wdst, a_src, a_dst, N);

  // x-space aggregation
  k_aggx<<<N, 256, 0, stream>>>(indptr, esrc, xb, a_src, a_dst, dis, AGG, N);

  // fused 2-layer MLP: AGG -> out
  k_mlp<<<(N + 63)/64, 512, 0, stream>>>(AGG, W1t, W2t, bias1, b_fus,
                                         (float*)d_out, N);
}